// Round 13
// baseline (2441.268 us; speedup 1.0000x reference)
//
#include <hip/hip_runtime.h>
#include <cstdint>

#define T_STEPS 400
#define B_SZ    256
#define NIN_SZ  64
#define H_SZ    512
#define NOUT_SZ 16
#define NEXC    409            // int(0.8*512)
#define MEMBERS 8              // column-slice members per group
#define GROUPS  32             // batch groups
#define BG      8              // batches per group
#define CSL     64             // columns per member
#define NTHR    512
#define NBLK    (GROUPS * MEMBERS)   // 256 WGs = 1/CU, all resident: no deadlock
#define KEXT    576            // 512 recurrent + 64 input rows
#define KR      18             // K rows per thread-kg (576 / 32)
#define TAG_BASE 0x5A5A0000u
#define ESC_SWEEPS 48          // failed fast sweeps before sticky escalation

// cross-kg butterfly: kg low bits are lane bits 4,5 (kg = tid>>4)
#define RED4(v)                                                        \
    v.x += __shfl_xor(v.x, 16); v.y += __shfl_xor(v.y, 16);            \
    v.z += __shfl_xor(v.z, 16); v.w += __shfl_xor(v.w, 16);            \
    v.x += __shfl_xor(v.x, 32); v.y += __shfl_xor(v.y, 32);            \
    v.z += __shfl_xor(v.z, 32); v.w += __shfl_xor(v.w, 32);

// macro params must not collide with member names x/y/z/w (R7 lesson)
#define FMA4V(P, Q, s)                                                 \
    P.x = fmaf(Q.x, s, P.x); P.y = fmaf(Q.y, s, P.y);                  \
    P.z = fmaf(Q.z, s, P.z); P.w = fmaf(Q.w, s, P.w);

// 8-slot poll sweep; F = cache flags. "sc0" = L1-bypass, served by the
// XCD-shared L2 (fast rendezvous for same-XCD members). "sc0 sc1" =
// L2-bypass, served by the chip coherence point (always correct: the
// publish stores are sc0 sc1 so the data is guaranteed there).
#define POLL8(F)                                                       \
    asm volatile(                                                      \
        "global_load_dwordx2 %0, %8,  off " F "\n\t"                   \
        "global_load_dwordx2 %1, %9,  off " F "\n\t"                   \
        "global_load_dwordx2 %2, %10, off " F "\n\t"                   \
        "global_load_dwordx2 %3, %11, off " F "\n\t"                   \
        "global_load_dwordx2 %4, %12, off " F "\n\t"                   \
        "global_load_dwordx2 %5, %13, off " F "\n\t"                   \
        "global_load_dwordx2 %6, %14, off " F "\n\t"                   \
        "global_load_dwordx2 %7, %15, off " F "\n\t"                   \
        "s_waitcnt vmcnt(0)"                                           \
        : "=&v"(v0), "=&v"(v1), "=&v"(v2), "=&v"(v3),                  \
          "=&v"(v4), "=&v"(v5), "=&v"(v6), "=&v"(v7)                   \
        : "v"(q0), "v"(q1), "v"(q2), "v"(q3),                          \
          "v"(q4), "v"(q5), "v"(q6), "v"(q7)                           \
        : "memory")

// ---------------------------------------------------------------------------
// 256 WGs = 32 batch-groups x 8 column-members. m=bid>>5, g=bid&31:
// members occupy bids {g, g+32, ...} -> all share bid%8 -> same XCD (perf
// heuristic only); grid == CU count -> all WGs resident -> deadlock-free.
// W slice (576x64, 72 floats/thread) in registers, asm-pinned.
// CODEGEN LAW (R4..R11): only __launch_bounds__(512,2) holds W resident.
// Exchange: tagged (tag<<32)|hp packets, stores sc0 sc1 (chip-coherent).
// Poll loads start sc0-only (XCD L2 rendezvous, ~8x less IC traffic); tag
// mismatch on a perpetually-stale line triggers sticky per-wave escalation
// to sc0 sc1 after ESC_SWEEPS failed sweeps -> worst case == R12 behavior.
// Skew bound 1 step -> parity-2 buffer safe; tags/values replay-invariant.
// ---------------------------------------------------------------------------
__global__ __launch_bounds__(NTHR, 2)
void biornn_main(const float* __restrict__ x,
                 const float* __restrict__ noise,
                 const float* __restrict__ wrnn_raw,
                 const float* __restrict__ win_raw,
                 const float* __restrict__ brnn,
                 uint64_t* __restrict__ pkt,     // [2][B_SZ][H_SZ] tagged hp
                 float* __restrict__ out_h,
                 float* __restrict__ out_sx,
                 float* __restrict__ out_su)
{
    __shared__ __align__(16) float hpT[KEXT * BG];     // [k][b]  18 KB
    __shared__ __align__(16) float pbuf[8 * BG * 64];  // [wv][b][cc] 16 KB
    __shared__ float brnn_l[CSL];

    const int tid = threadIdx.x;
    const int bid = blockIdx.x;
    const int m   = bid >> 5;          // member slice; group shares XCD
    const int g   = bid & 31;          // batch group
    const int c0  = m * CSL;
    const int b0  = g * BG;

    const int kg  = tid >> 4;          // K-split group 0..31
    const int cg4 = (tid & 15) * 4;    // 4 owned cols within slice
    const int wv  = tid >> 6;          // wave 0..7
    const int cb  = tid >> 6;          // owner batch 0..7
    const int cc  = tid & 63;          // owner local col

    // ---- one-time: W slice into registers (relu + Dale sign inline) ----
    float4 Wv[KR];
#pragma unroll
    for (int i = 0; i < KR; ++i) {
        const int k = kg * KR + i;
        const float* src = (k < H_SZ)
            ? &wrnn_raw[(size_t)k * H_SZ + c0 + cg4]
            : &win_raw[(size_t)(k - H_SZ) * H_SZ + c0 + cg4];
        float4 v = *(const float4*)src;
        const float sgn = (k < H_SZ && k >= NEXC) ? -1.0f : 1.0f;
        Wv[i] = make_float4(fmaxf(v.x, 0.f) * sgn, fmaxf(v.y, 0.f) * sgn,
                            fmaxf(v.z, 0.f) * sgn, fmaxf(v.w, 0.f) * sgn);
    }
#pragma unroll
    for (int i = 0; i < KR; ++i)       // pin vs rematerialization (R4 bug)
        asm volatile("" : "+v"(Wv[i].x), "+v"(Wv[i].y),
                          "+v"(Wv[i].z), "+v"(Wv[i].w));

    if (tid < CSL) brnn_l[tid] = brnn[c0 + tid];

    // STP constants by column parity (c0 multiple of 64 -> parity(tid) works
    // for both hpT row tid and owner column c0+cc)
    const bool  fac   = ((tid & 1) == 0);
    const float Uj    = fac ? 0.15f : 0.45f;
    const float a_stf = fac ? (10.0f / 1500.0f) : (10.0f / 200.0f);
    const float a_std = fac ? (10.0f / 200.0f)  : (10.0f / 1500.0f);

    // ---- prologue: syn(0) from (h=0.1, sx=1, su=U); hp(0) by parity ----
    float h = 0.1f, sx, su;
    {
        float sxn = 1.0f - 0.01f * Uj * 1.0f * 0.1f;
        float sun = Uj + 0.01f * Uj * (1.0f - Uj) * 0.1f;
        sx = fminf(fmaxf(sxn, 0.0f), 1.0f);
        su = fminf(fmaxf(sun, 0.0f), 1.0f);
        const float hp0 = su * sx * 0.1f;      // row parity == tid parity
        ((float4*)hpT)[tid * 2]     = make_float4(hp0, hp0, hp0, hp0);
        ((float4*)hpT)[tid * 2 + 1] = make_float4(hp0, hp0, hp0, hp0);
        const size_t ob = (size_t)(b0 + cb) * H_SZ + c0 + cc;      // t = 0
        out_sx[ob] = sx;
        out_su[ob] = su;
    }
    // x stagers: all 512 threads, (batch tid>>6, input col tid&63)
    float xreg = x[(size_t)(b0 + (tid >> 6)) * NIN_SZ + (tid & 63)];

    bool slowmode = false;             // sticky poll-path escalation

    for (int t = 0; t < T_STEPS; ++t) {
        // stage x(t) into hpT input rows (prefetched previous step)
        hpT[(H_SZ + (tid & 63)) * BG + (tid >> 6)] = xreg;
        __syncthreads();                                   // bar0: hpT(t) ready

        const float nz = noise[((size_t)t * B_SZ + b0 + cb) * H_SZ + c0 + cc];

        // ---- phase B: matvec, W in registers, hpT broadcast reads ----
        float4 a0 = make_float4(0.f, 0.f, 0.f, 0.f);
        float4 a1 = a0, a2 = a0, a3 = a0, a4 = a0, a5 = a0, a6 = a0, a7 = a0;
        {
            const float4* hp4 = (const float4*)hpT;
            const int kb = kg * KR;
#pragma unroll
            for (int i = 0; i < KR; ++i) {
                const float4 hL = hp4[(kb + i) * 2];       // batches 0..3
                const float4 hH = hp4[(kb + i) * 2 + 1];   // batches 4..7
                const float4 wq = Wv[i];
                FMA4V(a0, wq, hL.x)
                FMA4V(a1, wq, hL.y)
                FMA4V(a2, wq, hL.z)
                FMA4V(a3, wq, hL.w)
                FMA4V(a4, wq, hH.x)
                FMA4V(a5, wq, hH.y)
                FMA4V(a6, wq, hH.z)
                FMA4V(a7, wq, hH.w)
            }
        }
        // prefetch x(t+1) while FMAs retire
        if (t + 1 < T_STEPS)
            xreg = x[((size_t)(t + 1) * B_SZ + b0 + (tid >> 6)) * NIN_SZ + (tid & 63)];

        // ---- cross-kg reduction: 4 kgs per wave via shuffles ----
        RED4(a0) RED4(a1) RED4(a2) RED4(a3)
        RED4(a4) RED4(a5) RED4(a6) RED4(a7)
        if ((tid & 48) == 0) {                 // lanes 0..15 of each wave
            *(float4*)&pbuf[(wv * BG + 0) * 64 + cg4] = a0;
            *(float4*)&pbuf[(wv * BG + 1) * 64 + cg4] = a1;
            *(float4*)&pbuf[(wv * BG + 2) * 64 + cg4] = a2;
            *(float4*)&pbuf[(wv * BG + 3) * 64 + cg4] = a3;
            *(float4*)&pbuf[(wv * BG + 4) * 64 + cg4] = a4;
            *(float4*)&pbuf[(wv * BG + 5) * 64 + cg4] = a5;
            *(float4*)&pbuf[(wv * BG + 6) * 64 + cg4] = a6;
            *(float4*)&pbuf[(wv * BG + 7) * 64 + cg4] = a7;
        }
        __syncthreads();                                   // bar1: pbuf ready

        // ---- phase C: combine, membrane, STP(t+1), publish tagged packet ----
        {
            float s = brnn_l[cc];
#pragma unroll
            for (int q = 0; q < 8; ++q)
                s += pbuf[(q * BG + cb) * 64 + cc];
            const float hn = fmaxf(0.9f * h + 0.1f * s + nz, 0.0f);
            h = hn;
            if (t + 1 < T_STEPS) {
                float sxn = sx + a_std * (1.0f - sx) - 0.01f * su * sx * hn;
                float sun = su + a_stf * (Uj - su)   + 0.01f * Uj * (1.0f - su) * hn;
                sx = fminf(fmaxf(sxn, 0.0f), 1.0f);
                su = fminf(fmaxf(sun, 0.0f), 1.0f);
                const float hp = su * sx * hn;
                const uint64_t pk =
                    ((uint64_t)(TAG_BASE + (unsigned)(t + 1)) << 32) |
                    (uint64_t)__float_as_uint(hp);
                uint64_t* sp = pkt +
                    ((size_t)((t + 1) & 1) * B_SZ + b0 + cb) * H_SZ + c0 + cc;
                asm volatile("global_store_dwordx2 %0, %1, off sc0 sc1"
                             :: "v"(sp), "v"(pk) : "memory");
            }
        }
        if (t + 1 >= T_STEPS) {
            out_h[((size_t)t * B_SZ + b0 + cb) * H_SZ + c0 + cc] = h;
            break;
        }

        // ---- outputs + drain: one vmcnt(0) covers outputs, prefetch and
        // the publish store, so poll iterations wait only on themselves ----
        {
            out_h[((size_t)t * B_SZ + b0 + cb) * H_SZ + c0 + cc] = h;
            const size_t ob = ((size_t)(t + 1) * B_SZ + b0 + cb) * H_SZ + c0 + cc;
            out_sx[ob] = sx;
            out_su[ob] = su;
        }
        asm volatile("s_waitcnt vmcnt(0)" ::: "memory");

        // ---- gather hp(t+1): poll 8 tagged slots (row tid x 8 batches).
        // Fast path: sc0 loads rendezvous in the XCD-shared L2. If the line
        // never refreshes (XCD assumption broken), escalate stickily to
        // sc0 sc1 — stores are chip-coherent, so that path always succeeds.
        {
            const unsigned want = TAG_BASE + (unsigned)(t + 1);
            uint64_t* pr = pkt + ((size_t)((t + 1) & 1) * B_SZ + b0) * H_SZ + tid;
            uint64_t* q0 = pr;
            uint64_t* q1 = pr + 1 * H_SZ;
            uint64_t* q2 = pr + 2 * H_SZ;
            uint64_t* q3 = pr + 3 * H_SZ;
            uint64_t* q4 = pr + 4 * H_SZ;
            uint64_t* q5 = pr + 5 * H_SZ;
            uint64_t* q6 = pr + 6 * H_SZ;
            uint64_t* q7 = pr + 7 * H_SZ;
            uint64_t v0, v1, v2, v3, v4, v5, v6, v7;
            int sweeps = 0;
            while (true) {
                if (!slowmode) { POLL8("sc0"); }
                else           { POLL8("sc0 sc1"); }
                const bool ok = ((unsigned)(v0 >> 32) == want) &
                                ((unsigned)(v1 >> 32) == want) &
                                ((unsigned)(v2 >> 32) == want) &
                                ((unsigned)(v3 >> 32) == want) &
                                ((unsigned)(v4 >> 32) == want) &
                                ((unsigned)(v5 >> 32) == want) &
                                ((unsigned)(v6 >> 32) == want) &
                                ((unsigned)(v7 >> 32) == want);
                if (__all(ok)) break;
                if (++sweeps > ESC_SWEEPS) slowmode = true;   // sticky
            }
            ((float4*)hpT)[tid * 2] =
                make_float4(__uint_as_float((unsigned)v0),
                            __uint_as_float((unsigned)v1),
                            __uint_as_float((unsigned)v2),
                            __uint_as_float((unsigned)v3));
            ((float4*)hpT)[tid * 2 + 1] =
                make_float4(__uint_as_float((unsigned)v4),
                            __uint_as_float((unsigned)v5),
                            __uint_as_float((unsigned)v6),
                            __uint_as_float((unsigned)v7));
        }
        // next bar0 separates gather/x-stage writes from phase-B reads
    }
}

// ---------------------------------------------------------------------------
// logits[t,b,:] = h[t,b,:] @ relu(W_out) + bout  (overwrites the pkt scratch)
// ---------------------------------------------------------------------------
__global__ __launch_bounds__(256)
void logits_k(const float* __restrict__ h, const float* __restrict__ wout_raw,
              const float* __restrict__ bout, float* __restrict__ out) {
    __shared__ float wl[H_SZ * 17];    // padded stride 17
    __shared__ float bl[NOUT_SZ];
    const int tid = threadIdx.x;
    for (int i = tid; i < H_SZ * NOUT_SZ; i += 256)
        wl[(i >> 4) * 17 + (i & 15)] = fmaxf(wout_raw[i], 0.0f);
    if (tid < NOUT_SZ) bl[tid] = bout[tid];
    __syncthreads();
    const size_t row = (size_t)blockIdx.x * 16 + (tid >> 4);
    const int o = tid & 15;
    const float* hr = h + row * H_SZ;
    float s = bl[o];
#pragma unroll 8
    for (int jj = 0; jj < H_SZ; ++jj)
        s = fmaf(hr[jj], wl[jj * 17 + o], s);
    out[row * NOUT_SZ + o] = s;
}

extern "C" void kernel_launch(void* const* d_in, const int* in_sizes, int n_in,
                              void* d_out, int out_size, void* d_ws, size_t ws_size,
                              hipStream_t stream) {
    const float* x     = (const float*)d_in[0];
    const float* noise = (const float*)d_in[1];
    const float* W_in  = (const float*)d_in[2];
    const float* W_rnn = (const float*)d_in[3];
    const float* b_rnn = (const float*)d_in[4];
    const float* W_out = (const float*)d_in[5];
    const float* b_out = (const float*)d_in[6];

    float* out_logits = (float*)d_out;
    float* out_h  = out_logits + (size_t)T_STEPS * B_SZ * NOUT_SZ;
    float* out_sx = out_h  + (size_t)T_STEPS * B_SZ * H_SZ;
    float* out_su = out_sx + (size_t)T_STEPS * B_SZ * H_SZ;

    // pkt scratch: first 2 MB of the 6.55 MB logits region; fully
    // overwritten by logits_k afterwards.
    uint64_t* pkt = (uint64_t*)out_logits;

    biornn_main<<<NBLK, NTHR, 0, stream>>>(x, noise, W_rnn, W_in, b_rnn,
                                           pkt, out_h, out_sx, out_su);
    logits_k<<<(T_STEPS * B_SZ) / 16, 256, 0, stream>>>(
        out_h, W_out, b_out, out_logits);
}